// Round 4
// baseline (53.085 us; speedup 1.0000x reference)
//
#include <hip/hip_runtime.h>

// BERT_CRF, oct-partitioned, VALU emissions (no MFMA). B=64,T=512,H=768,L=9.
//
// Why no MFMA: total GEMM FLOPs = 0.45 GF = 2.9 us at vector-fp32 rate, vs
// 16 us memory floor -> memory-bound. The MFMA fragment layout forces each
// load instruction to gather 16 rows x 64B segments (16 cache lines per
// quarter-wave) which is TA-request-rate limited at ~0.8-1.6 TB/s (rounds
// 0/2/3 all identical at ~62 us profiled regardless of pipeline depth).
// Here: wave = one row, lane i loads row[4i..4i+4) -> 1KB contiguous per
// load instruction (the fill-kernel pattern that hits 87% of HBM peak).
//
// K1 emis_o_kernel: grid 512 = (b, oct), 256 threads (4 waves x 16 rows).
//   - W (9x768 fp32) held in 108 VGPRs/lane (wreg[3][9], static indexing),
//     loaded once from L2 at wave start.
//   - Per row: 3x float4 contiguous loads, 108 FMA into 9 accs, 6-level
//     __shfl_xor butterfly, lane l<9 writes exp(acc[l]+bias[l]) -> ldsE.
//   - Wave wid's 16 rows == CRF chunk wid: each wave computes its own
//     16-step chunk product (lanes 0..8, proven scaled-product code) with
//     NO barrier (own-wave LDS data). One __syncthreads, then wave 0
//     pair-combines 4->2->1 (proven code) -> oct matrix to global.
// K2 comb_kernel: byte-identical to round 3 (proven): octs->quarters->
//   serial fold -> partial[b]; election reduce -> out.

#define Bn 64
#define Tn 512
#define Hn 768
#define Ln 9
#define EMS 12     // padded LDS emission row stride (floats)
#define OT 64      // timesteps per block
#define NCHO 4     // chunks per oct (= waves per block)

// Proven pair-combine: (A,lgA) then (B,lgB) -> out (row-scaled) + outLg.
__device__ __forceinline__ void pair_combine(
    const float (*MA)[Ln], const float* lgA,
    const float (*MB)[Ln], const float* lgB,
    int r, float* outM, float* outLg)
{
    float mB = lgB[0];
#pragma unroll
    for (int k = 1; k < 9; ++k) mB = fmaxf(mB, lgB[k]);
    float tA[9];
#pragma unroll
    for (int k = 0; k < 9; ++k) tA[k] = MA[r][k] * __expf(lgB[k] - mB);
    float v[9];
#pragma unroll
    for (int jj = 0; jj < 9; ++jj) {
        float acc = tA[0] * MB[0][jj];
#pragma unroll
        for (int k = 1; k < 9; ++k) acc += tA[k] * MB[k][jj];
        v[jj] = acc;
    }
    float mx = v[0];
#pragma unroll
    for (int jj = 1; jj < 9; ++jj) mx = fmaxf(mx, v[jj]);
    float inv = 1.f / mx;
#pragma unroll
    for (int jj = 0; jj < 9; ++jj) outM[jj] = v[jj] * inv;
    *outLg = lgA[r] + mB + __logf(mx);
}

// ---------------- K1: per-(batch,oct) emissions + chunk products ----------------
__global__ __launch_bounds__(256) void emis_o_kernel(
    const float* __restrict__ wv, const float* __restrict__ Wm,
    const float* __restrict__ bias, const int* __restrict__ mask,
    const int* __restrict__ label, const float* __restrict__ trans,
    const float* __restrict__ startT,
    float* __restrict__ Mq, float* __restrict__ lgq,
    float* __restrict__ numq, int* __restrict__ msq,
    float* __restrict__ em0, int* __restrict__ cnt)
{
    __shared__ __align__(16) float ldsE[OT][EMS];   // exp(emissions)
    __shared__ int   ldsM[OT];                      // mask slice
    __shared__ float sM[NCHO][Ln][Ln];              // chunk product matrices
    __shared__ float sLg[NCHO][Ln];                 // chunk row log-scales
    __shared__ float s2M[2][Ln][Ln];
    __shared__ float s2Lg[2][Ln];
    __shared__ float sp[4];
    __shared__ int   si[4];

    const int tid   = threadIdx.x;
    const int lane  = tid & 63;
    const int wid   = tid >> 6;
    const int bid   = blockIdx.x;
    const int b     = bid >> 3;
    const int o     = bid & 7;
    const int tbase = o * OT;

    if (bid == 0 && tid == 0) cnt[0] = 0;    // K2 runs strictly after K1

    // ---- W in registers: wreg[r][l] = W[l][r*256 + lane*4 .. +4) ----
    // 27 independent float4 loads (L2-hot after first blocks), 108 VGPRs,
    // all accesses below use static indices (no scratch).
    float4 wreg[3][9];
#pragma unroll
    for (int r = 0; r < 3; ++r)
#pragma unroll
        for (int l = 0; l < 9; ++l)
            wreg[r][l] = *reinterpret_cast<const float4*>(
                Wm + l * Hn + r * 256 + (lane << 2));

    const float biasv = (lane < Ln) ? bias[lane] : 0.f;

    // ---- emission: wave wid computes rows [bid*64 + wid*16, +16) ----
    const float* rowp = wv + (size_t)(bid * OT + wid * 16) * Hn + (lane << 2);

#pragma unroll 2
    for (int row = 0; row < 16; ++row) {
        const float* src = rowp + row * Hn;
        float4 x0 = *reinterpret_cast<const float4*>(src);        // 1KB/wave
        float4 x1 = *reinterpret_cast<const float4*>(src + 256);  // contiguous
        float4 x2 = *reinterpret_cast<const float4*>(src + 512);
        float acc[9];
#pragma unroll
        for (int l = 0; l < 9; ++l) {
            float a = x0.x * wreg[0][l].x;
            a += x0.y * wreg[0][l].y; a += x0.z * wreg[0][l].z; a += x0.w * wreg[0][l].w;
            a += x1.x * wreg[1][l].x; a += x1.y * wreg[1][l].y;
            a += x1.z * wreg[1][l].z; a += x1.w * wreg[1][l].w;
            a += x2.x * wreg[2][l].x; a += x2.y * wreg[2][l].y;
            a += x2.z * wreg[2][l].z; a += x2.w * wreg[2][l].w;
            acc[l] = a;
        }
        // 64-lane butterfly: every lane ends with all 9 totals
#pragma unroll
        for (int off = 32; off > 0; off >>= 1) {
#pragma unroll
            for (int l = 0; l < 9; ++l) acc[l] += __shfl_xor(acc[l], off);
        }
        float v = acc[0];
#pragma unroll
        for (int l = 1; l < 9; ++l) v = (lane == l) ? acc[l] : v;
        if (lane < Ln) ldsE[wid * 16 + row][lane] = __expf(v + biasv);
    }

    // ---- numerator partials + mask staging (lanes 0..15, own rows) ----
    {
        float part = 0.f; int ms = 0;
        if (lane < 16) {
            const int lrow = wid * 16 + lane;
            const int gt   = tbase + lrow;
            const int tag  = label[b * Tn + gt];
            const int mk   = mask[b * Tn + gt];
            ldsM[lrow] = mk; ms = mk;
            if (gt == 0) {
                part = startT[tag] + __logf(ldsE[0][tag]);
            } else if (mk) {
                const int prev = label[b * Tn + gt - 1];
                part = trans[prev * Ln + tag] + __logf(ldsE[lrow][tag]);
            }
        }
#pragma unroll
        for (int off = 32; off > 0; off >>= 1) {
            part += __shfl_xor(part, off);
            ms   += __shfl_xor(ms, off);
        }
        if (lane == 0) { sp[wid] = part; si[wid] = ms; }
    }

    // ---- chunk product: wave wid == chunk wid, lanes 0..8, no barrier ----
    if (lane < Ln) {
        float Tr[81];
#pragma unroll
        for (int i = 0; i < 81; ++i) Tr[i] = __expf(trans[i]);
        const int r = lane;
        float v[9];
#pragma unroll
        for (int k = 0; k < 9; ++k) v[k] = (k == r) ? 1.f : 0.f;
        float lg = 0.f;
        const int sstart = (tbase + wid * 16 == 0) ? 1 : 0;   // skip t=0
        for (int s = sstart; s < 16; ++s) {
            const int lrow = wid * 16 + s;
            if (ldsM[lrow]) {
                float4 e0v = *reinterpret_cast<const float4*>(&ldsE[lrow][0]);
                float4 e1v = *reinterpret_cast<const float4*>(&ldsE[lrow][4]);
                float  e8  = ldsE[lrow][8];
                float e[9] = {e0v.x, e0v.y, e0v.z, e0v.w,
                              e1v.x, e1v.y, e1v.z, e1v.w, e8};
                float nv[9];
#pragma unroll
                for (int jj = 0; jj < 9; ++jj) {
                    float a2 = v[0] * Tr[jj];
#pragma unroll
                    for (int k = 1; k < 9; ++k) a2 += v[k] * Tr[k * 9 + jj];
                    nv[jj] = a2 * e[jj];
                }
                float mx = nv[0];
#pragma unroll
                for (int jj = 1; jj < 9; ++jj) mx = fmaxf(mx, nv[jj]);
                float inv = 1.f / mx;
#pragma unroll
                for (int jj = 0; jj < 9; ++jj) v[jj] = nv[jj] * inv;
                lg += __logf(mx);
            }
        }
#pragma unroll
        for (int jj = 0; jj < 9; ++jj) sM[wid][r][jj] = v[jj];
        sLg[wid][r] = lg;
    }
    __syncthreads();

    // ---- wave 0: combine 4 -> 2 -> 1 (proven, in-wave ordering) ----
    if (wid == 0) {
        if (o == 0 && lane < Ln) em0[b * Ln + lane] = ldsE[0][lane];
        if (lane < 2 * Ln) {
            const int p = lane / Ln, r = lane % Ln;
            float om[9], ol;
            pair_combine(sM[2 * p], sLg[2 * p], sM[2 * p + 1], sLg[2 * p + 1],
                         r, om, &ol);
#pragma unroll
            for (int jj = 0; jj < 9; ++jj) s2M[p][r][jj] = om[jj];
            s2Lg[p][r] = ol;
        }
        if (lane < Ln) {
            const int r = lane;
            float om[9], ol;
            pair_combine(s2M[0], s2Lg[0], s2M[1], s2Lg[1], r, om, &ol);
#pragma unroll
            for (int jj = 0; jj < 9; ++jj) Mq[bid * 81 + r * 9 + jj] = om[jj];
            lgq[bid * Ln + r] = ol;
        }
        if (lane == 0) {
            numq[bid] = sp[0] + sp[1] + sp[2] + sp[3];
            msq[bid]  = si[0] + si[1] + si[2] + si[3];
        }
    }
}

// ---------------- K2: combine 8 oct matrices per batch (round-3 verbatim) ----------------
__global__ __launch_bounds__(64) void comb_kernel(
    const float* __restrict__ Mq, const float* __restrict__ lgq,
    const float* __restrict__ numq, const int* __restrict__ msq,
    const float* __restrict__ em0, const int* __restrict__ label,
    const float* __restrict__ startT, const float* __restrict__ endT,
    float* __restrict__ partial, int* __restrict__ cnt, float* __restrict__ out)
{
    __shared__ float cO[8][Ln][Ln];
    __shared__ float cOl[8][Ln];
    __shared__ float cQ[4][Ln][Ln];
    __shared__ float cQl[4][Ln];
    __shared__ float cem[Ln];
    __shared__ float cnum[8];
    __shared__ int   cms[8];

    const int b = blockIdx.x, tid = threadIdx.x;

    for (int i = tid; i < 8 * 81; i += 64) ((float*)cO)[i]  = Mq[b * 648 + i];
    for (int i = tid; i < 8 * 9;  i += 64) ((float*)cOl)[i] = lgq[b * 72 + i];
    if (tid < Ln) cem[tid] = em0[b * Ln + tid];
    if (tid < 8) { cnum[tid] = numq[b * 8 + tid]; cms[tid] = msq[b * 8 + tid]; }
    __syncthreads();

    // pair-combine octs -> quarters
    if (tid < 4 * Ln) {
        const int p = tid / Ln, r = tid % Ln;
        float om[9], ol;
        pair_combine(cO[2 * p], cOl[2 * p], cO[2 * p + 1], cOl[2 * p + 1],
                     r, om, &ol);
#pragma unroll
        for (int jj = 0; jj < 9; ++jj) cQ[p][r][jj] = om[jj];
        cQl[p][r] = ol;
    }
    __syncthreads();

    // serial fold of 4 quarters + denominator
    if (tid < 16) {
        const int lj = tid;
        const float NEG = -1e30f;
        float la = (lj < Ln) ? (startT[lj] + __logf(cem[lj])) : NEG;
        for (int c = 0; c < 4; ++c) {
            float mc[9];
#pragma unroll
            for (int rr = 0; rr < 9; ++rr) mc[rr] = (lj < Ln) ? cQ[c][rr][lj] : 0.f;
            float x = (lj < Ln) ? (la + cQl[c][lj]) : NEG;
            float mm = x;
#pragma unroll
            for (int off = 1; off < 16; off <<= 1) mm = fmaxf(mm, __shfl_xor(mm, off, 16));
            float w = __expf(x - mm);                 // lj>=9 -> 0
            float sacc = 0.f;
#pragma unroll
            for (int rr = 0; rr < 9; ++rr) sacc += __shfl(w, rr, 16) * mc[rr];
            la = (lj < Ln) ? (mm + __logf(sacc)) : NEG;
        }
        float x = (lj < Ln) ? (la + endT[lj]) : NEG;
        float mm = x;
#pragma unroll
        for (int off = 1; off < 16; off <<= 1) mm = fmaxf(mm, __shfl_xor(mm, off, 16));
        float se = __expf(x - mm);
#pragma unroll
        for (int off = 1; off < 16; off <<= 1) se += __shfl_xor(se, off, 16);
        if (lj == 0) {
            float denom = mm + __logf(se);
            float numer = cnum[0] + cnum[1] + cnum[2] + cnum[3]
                        + cnum[4] + cnum[5] + cnum[6] + cnum[7];
            int   sm    = cms[0] + cms[1] + cms[2] + cms[3]
                        + cms[4] + cms[5] + cms[6] + cms[7];
            int   last  = label[b * Tn + sm - 1];
            partial[b]  = denom - (numer + endT[last]);   // = -llh[b]
        }
    }

    // last block reduces partials -> out (proven election pattern)
    int old = 0;
    if (tid == 0) {
        __threadfence();
        old = atomicAdd(cnt, 1);
    }
    old = __shfl(old, 0);
    if (old == Bn - 1) {
        __threadfence();                 // acquire: other blocks' partial[] visible
        float pv = partial[tid];
#pragma unroll
        for (int off = 32; off > 0; off >>= 1) pv += __shfl_xor(pv, off);
        if (tid == 0) out[0] = pv * (1.0f / Bn);
    }
}

extern "C" void kernel_launch(void* const* d_in, const int* in_sizes, int n_in,
                              void* d_out, int out_size, void* d_ws, size_t ws_size,
                              hipStream_t stream)
{
    // inputs: 0=length(unused) 1=word2vec 2=mask 3=label 4=W 5=b 6=start 7=end 8=trans
    const float* wv    = (const float*)d_in[1];
    const int*   mask  = (const int*)d_in[2];
    const int*   label = (const int*)d_in[3];
    const float* Wm    = (const float*)d_in[4];
    const float* bias  = (const float*)d_in[5];
    const float* st    = (const float*)d_in[6];
    const float* en    = (const float*)d_in[7];
    const float* tr    = (const float*)d_in[8];

    float* ws      = (float*)d_ws;
    float* Mq      = ws;                    // 512*81 = 41472
    float* lgq     = ws + 41472;            // 512*9  = 4608
    float* numq    = ws + 46080;            // 512
    int*   msq     = (int*)(ws + 46592);    // 512
    float* em0     = ws + 47104;            // 64*9 = 576
    float* partial = ws + 47680;            // 64
    int*   cnt     = (int*)(ws + 47744);    // 1
    float* out     = (float*)d_out;

    hipLaunchKernelGGL(emis_o_kernel, dim3(512), dim3(256), 0, stream,
                       wv, Wm, bias, mask, label, tr, st,
                       Mq, lgq, numq, msq, em0, cnt);
    hipLaunchKernelGGL(comb_kernel, dim3(Bn), dim3(64), 0, stream,
                       Mq, lgq, numq, msq, em0, label, st, en,
                       partial, cnt, out);
}